// Round 1
// baseline (1231.552 us; speedup 1.0000x reference)
//
#include <hip/hip_runtime.h>
#include <math.h>

constexpr int B = 32;
constexpr int NN = 2048;   // nodes
constexpr int E = 65536;   // edges
constexpr int VF = 36;     // padded vf row stride (34 used + 2 pad)
constexpr float SLOPE = 0.01f;

__device__ __forceinline__ float lrelu(float x) { return x > 0.f ? x : SLOPE * x; }

// ---------------- prep: transpose weights into [j][32] layout ----------------
__global__ __launch_bounds__(1024) void prep_kernel(
    const float* __restrict__ W1c, const float* __restrict__ W2c,
    const float* __restrict__ W1v, const float* __restrict__ W2v,
    const float* __restrict__ W1e, const float* __restrict__ W2e,
    const float* __restrict__ W1o,
    float* __restrict__ W1cT, float* __restrict__ W2cT,
    float* __restrict__ W1vT, float* __restrict__ W2vT,
    float* __restrict__ W1eT, float* __restrict__ W2eT,
    float* __restrict__ W1oT)
{
    int t = threadIdx.x;
    for (int i = t; i < 32 * 24; i += 1024) W1cT[(i % 24) * 32 + i / 24] = W1c[i];
    for (int i = t; i < 32 * 32; i += 1024) W2cT[(i % 32) * 32 + i / 32] = W2c[i];
    for (int i = t; i < 32 * 64; i += 1024) W1vT[(i % 64) * 32 + i / 64] = W1v[i];
    for (int i = t; i < 32 * 32; i += 1024) W2vT[(i % 32) * 32 + i / 32] = W2v[i];
    for (int i = t; i < 32 * 68; i += 1024) W1eT[(i % 68) * 32 + i / 68] = W1e[i];
    for (int i = t; i < 32 * 32; i += 1024) W2eT[(i % 32) * 32 + i / 32] = W2e[i];
    for (int i = t; i < 32 * 32; i += 1024) W1oT[(i % 32) * 32 + i / 32] = W1o[i];
}

// ---------------- CSR build ----------------
__global__ __launch_bounds__(256) void zero_kernel(int* __restrict__ cnt, int* __restrict__ cursor)
{
    int i = blockIdx.x * 256 + threadIdx.x;
    if (i < NN) { cnt[i] = 0; cursor[i] = 0; }
}

__global__ __launch_bounds__(256) void count_kernel(const int* __restrict__ edges, int* __restrict__ cnt)
{
    int e = blockIdx.x * 256 + threadIdx.x;
    if (e < E) atomicAdd(&cnt[edges[E + e]], 1);
}

__global__ __launch_bounds__(1024) void scan_kernel(const int* __restrict__ cnt, int* __restrict__ offs)
{
    __shared__ int s[1024];
    int t = threadIdx.x;                    // 1024 threads, each owns 2 entries
    int c0 = cnt[2 * t], c1 = cnt[2 * t + 1];
    int own = c0 + c1;
    s[t] = own;
    __syncthreads();
    int v = own;
    for (int d = 1; d < 1024; d <<= 1) {
        int add = (t >= d) ? s[t - d] : 0;
        __syncthreads();
        v += add;
        s[t] = v;
        __syncthreads();
    }
    int excl = v - own;                     // exclusive over pair-sums
    offs[2 * t] = excl;
    offs[2 * t + 1] = excl + c0;
}

__global__ __launch_bounds__(256) void fill_kernel(
    const int* __restrict__ edges, const int* __restrict__ offs,
    int* __restrict__ cursor, int* __restrict__ elist)
{
    int e = blockIdx.x * 256 + threadIdx.x;
    if (e < E) {
        int d = edges[E + e];
        int p = atomicAdd(&cursor[d], 1);
        elist[offs[d] + p] = edges[e];      // store src id directly
    }
}

// ---------------- vertex features: vf[b,n,0:34] ----------------
__global__ __launch_bounds__(256) void vertex_kernel(
    const float* __restrict__ vert,
    const float* __restrict__ Wx,  const float* __restrict__ bx,
    const float* __restrict__ Wy,  const float* __restrict__ by,
    const float* __restrict__ Wth, const float* __restrict__ bth,
    const float* __restrict__ b1c, const float* __restrict__ b2c,
    const float* __restrict__ b1v, const float* __restrict__ b2v,
    const float* __restrict__ W1cT, const float* __restrict__ W2cT,
    const float* __restrict__ W1vT, const float* __restrict__ W2vT,
    float* __restrict__ vf)
{
    int idx = blockIdx.x * 256 + threadIdx.x;
    if (idx >= B * NN) return;
    const float* v = vert + (size_t)idx * 11;
    float qk0 = v[0], qk1 = v[1], qk2 = v[2];
    float q00 = v[3], q01 = v[4], q02 = v[5];
    float qg0 = v[6], qg1 = v[7], qg2 = v[8];
    float col0 = v[9], col1 = v[10];

    float cf[64];
    #pragma unroll
    for (int half = 0; half < 2; ++half) {
        float a0 = half ? qg0 : q00;
        float a1 = half ? qg1 : q01;
        float a2 = half ? qg2 : q02;
        float c[24];
        #pragma unroll
        for (int k = 0; k < 8; ++k) {
            c[k]      = lrelu(qk0 * Wx[2 * k]  + a0 * Wx[2 * k + 1]  + bx[k]);
            c[8 + k]  = lrelu(qk1 * Wy[2 * k]  + a1 * Wy[2 * k + 1]  + by[k]);
            c[16 + k] = lrelu(qk2 * Wth[2 * k] + a2 * Wth[2 * k + 1] + bth[k]);
        }
        float h[32];
        #pragma unroll
        for (int o = 0; o < 32; ++o) h[o] = b1c[o];
        #pragma unroll
        for (int j = 0; j < 24; ++j) {
            float x = c[j];
            #pragma unroll
            for (int o = 0; o < 32; ++o) h[o] += x * W1cT[j * 32 + o];
        }
        #pragma unroll
        for (int o = 0; o < 32; ++o) h[o] = lrelu(h[o]);
        float g[32];
        #pragma unroll
        for (int o = 0; o < 32; ++o) g[o] = b2c[o];
        #pragma unroll
        for (int j = 0; j < 32; ++j) {
            float x = h[j];
            #pragma unroll
            for (int o = 0; o < 32; ++o) g[o] += x * W2cT[j * 32 + o];
        }
        #pragma unroll
        for (int o = 0; o < 32; ++o) cf[half * 32 + o] = lrelu(g[o]);
    }

    float v1[32];
    #pragma unroll
    for (int o = 0; o < 32; ++o) v1[o] = b1v[o];
    #pragma unroll
    for (int j = 0; j < 64; ++j) {
        float x = cf[j];
        #pragma unroll
        for (int o = 0; o < 32; ++o) v1[o] += x * W1vT[j * 32 + o];
    }
    #pragma unroll
    for (int o = 0; o < 32; ++o) v1[o] = lrelu(v1[o]);

    float v2[32];
    #pragma unroll
    for (int o = 0; o < 32; ++o) v2[o] = b2v[o];
    #pragma unroll
    for (int j = 0; j < 32; ++j) {
        float x = v1[j];
        #pragma unroll
        for (int o = 0; o < 32; ++o) v2[o] += x * W2vT[j * 32 + o];
    }

    float* __restrict__ row = vf + (size_t)idx * VF;
    #pragma unroll
    for (int o = 0; o < 32; ++o) row[o] = lrelu(v2[o]);
    row[32] = col0;
    row[33] = col1;
    row[34] = 0.f;
    row[35] = 0.f;
}

// ---------------- edge MLP + mean-aggregate + output MLP ----------------
__global__ __launch_bounds__(256) void edge_kernel(
    const float* __restrict__ vf,
    const int* __restrict__ elist, const int* __restrict__ offs, const int* __restrict__ cnt,
    const float* __restrict__ W1eT, const float* __restrict__ b1e,
    const float* __restrict__ W2eT, const float* __restrict__ b2e,
    const float* __restrict__ W1oT, const float* __restrict__ b1o,
    const float* __restrict__ W2o,  const float* __restrict__ b2o,
    float* __restrict__ fv)
{
    int idx = blockIdx.x * 256 + threadIdx.x;
    if (idx >= B * NN) return;
    int b = idx >> 11;
    int n = idx & (NN - 1);
    const float* __restrict__ vd = vf + (size_t)idx * VF;
    int start = offs[n];
    int c = cnt[n];

    float sum[32];
    #pragma unroll
    for (int o = 0; o < 32; ++o) sum[o] = 0.f;

    for (int k = 0; k < c; ++k) {
        int s = elist[start + k];
        const float* __restrict__ vs = vf + (size_t)(b * NN + s) * VF;
        float acc[32];
        #pragma unroll
        for (int o = 0; o < 32; ++o) acc[o] = b1e[o];
        // layer 1, src half (j = 0..33)
        #pragma unroll 2
        for (int j = 0; j < 34; ++j) {
            float x = vs[j];
            #pragma unroll
            for (int o = 0; o < 32; ++o) acc[o] += x * W1eT[j * 32 + o];
        }
        // layer 1, dst half (j = 34..67)
        #pragma unroll 2
        for (int j = 0; j < 34; ++j) {
            float x = vd[j];
            #pragma unroll
            for (int o = 0; o < 32; ++o) acc[o] += x * W1eT[(34 + j) * 32 + o];
        }
        #pragma unroll
        for (int o = 0; o < 32; ++o) acc[o] = fmaxf(acc[o], 0.f);   // relu
        // layer 2 (fully unrolled: acc is a register array)
        float acc2[32];
        #pragma unroll
        for (int o = 0; o < 32; ++o) acc2[o] = b2e[o];
        #pragma unroll
        for (int j = 0; j < 32; ++j) {
            float x = acc[j];
            #pragma unroll
            for (int o = 0; o < 32; ++o) acc2[o] += x * W2eT[j * 32 + o];
        }
        #pragma unroll
        for (int o = 0; o < 32; ++o) sum[o] += lrelu(acc2[o]);
    }

    float inv = 1.f / fmaxf((float)c, 1.f);
    float f1[32];
    #pragma unroll
    for (int o = 0; o < 32; ++o) f1[o] = b1o[o];
    #pragma unroll
    for (int j = 0; j < 32; ++j) {
        float x = sum[j] * inv;
        #pragma unroll
        for (int o = 0; o < 32; ++o) f1[o] += x * W1oT[j * 32 + o];
    }
    float f2 = b2o[0];
    #pragma unroll
    for (int j = 0; j < 32; ++j) f2 += fmaxf(f1[j], 0.f) * W2o[j];
    fv[idx] = lrelu(f2);
}

// ---------------- final: out[b] = sigmoid(dot(fv[b,:], Wg) + bg) ----------------
__global__ __launch_bounds__(256) void final_kernel(
    const float* __restrict__ fv, const float* __restrict__ Wg,
    const float* __restrict__ bg, float* __restrict__ out)
{
    int b = blockIdx.x;
    int t = threadIdx.x;
    float p = 0.f;
    for (int n = t; n < NN; n += 256) p += fv[(size_t)b * NN + n] * Wg[n];
    __shared__ float red[256];
    red[t] = p;
    __syncthreads();
    for (int s = 128; s > 0; s >>= 1) {
        if (t < s) red[t] += red[t + s];
        __syncthreads();
    }
    if (t == 0) {
        float x = red[0] + bg[0];
        out[b] = 1.f / (1.f + expf(-x));
    }
}

extern "C" void kernel_launch(void* const* d_in, const int* in_sizes, int n_in,
                              void* d_out, int out_size, void* d_ws, size_t ws_size,
                              hipStream_t stream)
{
    const float* vert = (const float*)d_in[0];
    const int*   edges = (const int*)d_in[1];
    const float* Wx  = (const float*)d_in[2];
    const float* bx  = (const float*)d_in[3];
    const float* Wy  = (const float*)d_in[4];
    const float* by  = (const float*)d_in[5];
    const float* Wth = (const float*)d_in[6];
    const float* bth = (const float*)d_in[7];
    const float* W1c = (const float*)d_in[8];
    const float* b1c = (const float*)d_in[9];
    const float* W2c = (const float*)d_in[10];
    const float* b2c = (const float*)d_in[11];
    const float* W1v = (const float*)d_in[12];
    const float* b1v = (const float*)d_in[13];
    const float* W2v = (const float*)d_in[14];
    const float* b2v = (const float*)d_in[15];
    const float* W1e = (const float*)d_in[16];
    const float* b1e = (const float*)d_in[17];
    const float* W2e = (const float*)d_in[18];
    const float* b2e = (const float*)d_in[19];
    const float* W1o = (const float*)d_in[20];
    const float* b1o = (const float*)d_in[21];
    const float* W2o = (const float*)d_in[22];
    const float* b2o = (const float*)d_in[23];
    const float* Wg  = (const float*)d_in[24];
    const float* bg  = (const float*)d_in[25];
    float* out = (float*)d_out;

    // workspace layout
    char* w = (char*)d_ws;
    float* vf   = (float*)w; w += (size_t)B * NN * VF * 4;
    float* fv   = (float*)w; w += (size_t)B * NN * 4;
    float* W1cT = (float*)w; w += 32 * 24 * 4;
    float* W2cT = (float*)w; w += 32 * 32 * 4;
    float* W1vT = (float*)w; w += 32 * 64 * 4;
    float* W2vT = (float*)w; w += 32 * 32 * 4;
    float* W1eT = (float*)w; w += 32 * 68 * 4;
    float* W2eT = (float*)w; w += 32 * 32 * 4;
    float* W1oT = (float*)w; w += 32 * 32 * 4;
    int* cnt    = (int*)w;   w += NN * 4;
    int* cursor = (int*)w;   w += NN * 4;
    int* offs   = (int*)w;   w += NN * 4;
    int* elist  = (int*)w;   w += E * 4;

    prep_kernel<<<1, 1024, 0, stream>>>(W1c, W2c, W1v, W2v, W1e, W2e, W1o,
                                        W1cT, W2cT, W1vT, W2vT, W1eT, W2eT, W1oT);
    zero_kernel<<<(NN + 255) / 256, 256, 0, stream>>>(cnt, cursor);
    count_kernel<<<E / 256, 256, 0, stream>>>(edges, cnt);
    scan_kernel<<<1, 1024, 0, stream>>>(cnt, offs);
    fill_kernel<<<E / 256, 256, 0, stream>>>(edges, offs, cursor, elist);

    vertex_kernel<<<(B * NN) / 256, 256, 0, stream>>>(
        vert, Wx, bx, Wy, by, Wth, bth, b1c, b2c, b1v, b2v,
        W1cT, W2cT, W1vT, W2vT, vf);

    edge_kernel<<<(B * NN) / 256, 256, 0, stream>>>(
        vf, elist, offs, cnt, W1eT, b1e, W2eT, b2e, W1oT, b1o, W2o, b2o, fv);

    final_kernel<<<B, 256, 0, stream>>>(fv, Wg, bg, out);
}

// Round 3
// 372.433 us; speedup vs baseline: 3.3068x; 3.3068x over previous
//
#include <hip/hip_runtime.h>
#include <math.h>

constexpr int B = 32;
constexpr int NN = 2048;   // nodes
constexpr int E = 65536;   // edges
constexpr float SLOPE = 0.01f;

__device__ __forceinline__ float lrelu(float x) { return x > 0.f ? x : SLOPE * x; }

__device__ __forceinline__ unsigned int pack_bf16(float lo, float hi) {
    unsigned int a = __float_as_uint(lo);
    unsigned int b = __float_as_uint(hi);
    a += 0x7fffu + ((a >> 16) & 1u);
    b += 0x7fffu + ((b >> 16) & 1u);
    return (a >> 16) | (b & 0xffff0000u);
}

__device__ __forceinline__ void unpack_bf16(unsigned int u, float& lo, float& hi) {
    lo = __uint_as_float(u << 16);
    hi = __uint_as_float(u & 0xffff0000u);
}

// ---------------- prep: transposed weights ----------------
__global__ __launch_bounds__(1024) void prep_kernel(
    const float* __restrict__ W1c, const float* __restrict__ W2c,
    const float* __restrict__ W1v, const float* __restrict__ W2v,
    const float* __restrict__ W1e, const float* __restrict__ W2e,
    const float* __restrict__ W1o,
    float* __restrict__ W1cT, float* __restrict__ W2cT,
    float* __restrict__ W1vT, float* __restrict__ W2vT,
    float* __restrict__ W1sT, float* __restrict__ W1dT,
    float* __restrict__ W2eT, float* __restrict__ W1oT)
{
    int t = threadIdx.x;
    for (int i = t; i < 32 * 24; i += 1024) W1cT[(i % 24) * 32 + i / 24] = W1c[i];
    for (int i = t; i < 32 * 32; i += 1024) W2cT[(i % 32) * 32 + i / 32] = W2c[i];
    for (int i = t; i < 32 * 64; i += 1024) W1vT[(i % 64) * 32 + i / 64] = W1v[i];
    for (int i = t; i < 32 * 32; i += 1024) W2vT[(i % 32) * 32 + i / 32] = W2v[i];
    for (int i = t; i < 32 * 68; i += 1024) {
        int o = i / 68, j = i % 68;
        if (j < 34) W1sT[j * 32 + o] = W1e[i];
        else        W1dT[(j - 34) * 32 + o] = W1e[i];
    }
    for (int i = t; i < 32 * 32; i += 1024) W2eT[(i % 32) * 32 + i / 32] = W2e[i];
    for (int i = t; i < 32 * 32; i += 1024) W1oT[(i % 32) * 32 + i / 32] = W1o[i];
}

// ---------------- zero sums + CSR counters ----------------
__global__ __launch_bounds__(256) void zero_kernel(float* __restrict__ sums,
                                                   int* __restrict__ cnt,
                                                   int* __restrict__ cursor)
{
    int i = blockIdx.x * 256 + threadIdx.x;          // 2048 blocks -> 524288 threads
    float4* s4 = (float4*)sums;
    s4[i] = make_float4(0.f, 0.f, 0.f, 0.f);         // covers B*NN*32 floats exactly
    if (i < NN) { cnt[i] = 0; cursor[i] = 0; }
}

__global__ __launch_bounds__(256) void count_kernel(const int* __restrict__ edges, int* __restrict__ cnt)
{
    int e = blockIdx.x * 256 + threadIdx.x;
    if (e < E) atomicAdd(&cnt[edges[E + e]], 1);
}

__global__ __launch_bounds__(1024) void scan_kernel(const int* __restrict__ cnt, int* __restrict__ offs)
{
    __shared__ int s[1024];
    int t = threadIdx.x;
    int c0 = cnt[2 * t], c1 = cnt[2 * t + 1];
    int own = c0 + c1;
    s[t] = own;
    __syncthreads();
    int v = own;
    for (int d = 1; d < 1024; d <<= 1) {
        int add = (t >= d) ? s[t - d] : 0;
        __syncthreads();
        v += add;
        s[t] = v;
        __syncthreads();
    }
    int excl = v - own;
    offs[2 * t] = excl;
    offs[2 * t + 1] = excl + c0;
}

__global__ __launch_bounds__(256) void fill_kernel(
    const int* __restrict__ edges, const int* __restrict__ offs,
    int* __restrict__ cursor, int* __restrict__ elist, int* __restrict__ dlist)
{
    int e = blockIdx.x * 256 + threadIdx.x;
    if (e < E) {
        int d = edges[E + e];
        int p = atomicAdd(&cursor[d], 1);
        elist[offs[d] + p] = edges[e];
        dlist[offs[d] + p] = d;
    }
}

// ---------------- vertex MLP + per-node edge-layer-1 projections ----------------
__global__ __launch_bounds__(256) void vertex_kernel(
    const float* __restrict__ vert,
    const float* __restrict__ Wx,  const float* __restrict__ bx,
    const float* __restrict__ Wy,  const float* __restrict__ by,
    const float* __restrict__ Wth, const float* __restrict__ bth,
    const float* __restrict__ b1c, const float* __restrict__ b2c,
    const float* __restrict__ b1v, const float* __restrict__ b2v,
    const float* __restrict__ b1e,
    const float* __restrict__ W1cT, const float* __restrict__ W2cT,
    const float* __restrict__ W1vT, const float* __restrict__ W2vT,
    const float* __restrict__ W1sT, const float* __restrict__ W1dT,
    unsigned int* __restrict__ asrc, unsigned int* __restrict__ adst)
{
    int idx = blockIdx.x * 256 + threadIdx.x;
    if (idx >= B * NN) return;
    const float* v = vert + (size_t)idx * 11;
    float qk0 = v[0], qk1 = v[1], qk2 = v[2];
    float q00 = v[3], q01 = v[4], q02 = v[5];
    float qg0 = v[6], qg1 = v[7], qg2 = v[8];
    float col0 = v[9], col1 = v[10];

    float cf[64];
    #pragma unroll
    for (int half = 0; half < 2; ++half) {
        float a0 = half ? qg0 : q00;
        float a1 = half ? qg1 : q01;
        float a2 = half ? qg2 : q02;
        float c[24];
        #pragma unroll
        for (int k = 0; k < 8; ++k) {
            c[k]      = lrelu(qk0 * Wx[2 * k]  + a0 * Wx[2 * k + 1]  + bx[k]);
            c[8 + k]  = lrelu(qk1 * Wy[2 * k]  + a1 * Wy[2 * k + 1]  + by[k]);
            c[16 + k] = lrelu(qk2 * Wth[2 * k] + a2 * Wth[2 * k + 1] + bth[k]);
        }
        float h[32];
        #pragma unroll
        for (int o = 0; o < 32; ++o) h[o] = b1c[o];
        #pragma unroll
        for (int j = 0; j < 24; ++j) {
            float x = c[j];
            #pragma unroll
            for (int o = 0; o < 32; ++o) h[o] += x * W1cT[j * 32 + o];
        }
        #pragma unroll
        for (int o = 0; o < 32; ++o) h[o] = lrelu(h[o]);
        float g[32];
        #pragma unroll
        for (int o = 0; o < 32; ++o) g[o] = b2c[o];
        #pragma unroll
        for (int j = 0; j < 32; ++j) {
            float x = h[j];
            #pragma unroll
            for (int o = 0; o < 32; ++o) g[o] += x * W2cT[j * 32 + o];
        }
        #pragma unroll
        for (int o = 0; o < 32; ++o) cf[half * 32 + o] = lrelu(g[o]);
    }

    float v1[32];
    #pragma unroll
    for (int o = 0; o < 32; ++o) v1[o] = b1v[o];
    #pragma unroll
    for (int j = 0; j < 64; ++j) {
        float x = cf[j];
        #pragma unroll
        for (int o = 0; o < 32; ++o) v1[o] += x * W1vT[j * 32 + o];
    }
    #pragma unroll
    for (int o = 0; o < 32; ++o) v1[o] = lrelu(v1[o]);

    float v2[32];
    #pragma unroll
    for (int o = 0; o < 32; ++o) v2[o] = b2v[o];
    #pragma unroll
    for (int j = 0; j < 32; ++j) {
        float x = v1[j];
        #pragma unroll
        for (int o = 0; o < 32; ++o) v2[o] += x * W2vT[j * 32 + o];
    }

    float vfr[34];
    #pragma unroll
    for (int o = 0; o < 32; ++o) vfr[o] = lrelu(v2[o]);
    vfr[32] = col0;
    vfr[33] = col1;

    // project onto edge-layer-1: asrc = vfr @ W1s^T ; adst = vfr @ W1d^T + b1e
    float as[32], ad[32];
    #pragma unroll
    for (int o = 0; o < 32; ++o) { as[o] = 0.f; ad[o] = b1e[o]; }
    #pragma unroll
    for (int j = 0; j < 34; ++j) {
        float x = vfr[j];
        #pragma unroll
        for (int o = 0; o < 32; ++o) {
            as[o] += x * W1sT[j * 32 + o];
            ad[o] += x * W1dT[j * 32 + o];
        }
    }

    unsigned int* ps = asrc + ((size_t)idx << 4);   // 16 uints = 32 bf16
    unsigned int* pd = adst + ((size_t)idx << 4);
    #pragma unroll
    for (int q = 0; q < 16; ++q) {
        ps[q] = pack_bf16(as[2 * q], as[2 * q + 1]);
        pd[q] = pack_bf16(ad[2 * q], ad[2 * q + 1]);
    }
}

// ---------------- edge: lane-per-edge, layer2 GEMV, segmented wave reduce ----------------
__global__ __launch_bounds__(256) void edge_kernel(
    const unsigned int* __restrict__ asrc, const unsigned int* __restrict__ adst,
    const int* __restrict__ elist, const int* __restrict__ dlist,
    const float* __restrict__ W2eT, const float* __restrict__ b2e,
    float* __restrict__ sums)
{
    int gid = blockIdx.x * 256 + threadIdx.x;       // B*E threads, b-major
    int lane = threadIdx.x & 63;
    int b = gid >> 16;                              // E = 65536
    int e = gid & (E - 1);
    int src = elist[e];
    int dst = dlist[e];

    const uint4* ps = (const uint4*)(asrc + (((size_t)b * NN + src) << 4));
    const uint4* pd = (const uint4*)(adst + (((size_t)b * NN + dst) << 4));

    float h[32];
    #pragma unroll
    for (int q = 0; q < 4; ++q) {
        uint4 ua = ps[q];
        uint4 ud = pd[q];
        float a0, a1, d0, d1;
        unpack_bf16(ua.x, a0, a1); unpack_bf16(ud.x, d0, d1);
        h[q * 8 + 0] = fmaxf(a0 + d0, 0.f); h[q * 8 + 1] = fmaxf(a1 + d1, 0.f);
        unpack_bf16(ua.y, a0, a1); unpack_bf16(ud.y, d0, d1);
        h[q * 8 + 2] = fmaxf(a0 + d0, 0.f); h[q * 8 + 3] = fmaxf(a1 + d1, 0.f);
        unpack_bf16(ua.z, a0, a1); unpack_bf16(ud.z, d0, d1);
        h[q * 8 + 4] = fmaxf(a0 + d0, 0.f); h[q * 8 + 5] = fmaxf(a1 + d1, 0.f);
        unpack_bf16(ua.w, a0, a1); unpack_bf16(ud.w, d0, d1);
        h[q * 8 + 6] = fmaxf(a0 + d0, 0.f); h[q * 8 + 7] = fmaxf(a1 + d1, 0.f);
    }

    float m[32];
    #pragma unroll
    for (int o = 0; o < 32; ++o) m[o] = b2e[o];
    #pragma unroll
    for (int j = 0; j < 32; ++j) {
        float x = h[j];
        #pragma unroll
        for (int o = 0; o < 32; ++o) m[o] += x * W2eT[j * 32 + o];
    }
    #pragma unroll
    for (int o = 0; o < 32; ++o) m[o] = lrelu(m[o]);

    // segmented reduction over the wave: edges are CSR-sorted so equal-dst
    // lanes form contiguous runs. Inclusive segmented scan via shfl_up.
    int prev_dst = __shfl_up(dst, 1);
    bool head = (lane == 0) || (prev_dst != dst);
    unsigned long long H = __ballot(head);
    unsigned long long mask = (2ULL << lane) - 1ULL;     // bits 0..lane
    int headlane = 63 - __builtin_clzll(H & mask);

    #pragma unroll
    for (int s = 1; s < 64; s <<= 1) {
        bool take = (lane - s) >= headlane;
        #pragma unroll
        for (int o = 0; o < 32; ++o) {
            float t = __shfl_up(m[o], s);
            if (take) m[o] += t;
        }
    }

    int next_head = __shfl_down((int)head, 1);
    bool last = (lane == 63) || next_head;
    if (last) {
        float* sp = sums + (((size_t)b * NN + dst) << 5);
        #pragma unroll
        for (int o = 0; o < 32; ++o) atomicAdd(sp + o, m[o]);
    }
}

// ---------------- per-node output MLP ----------------
__global__ __launch_bounds__(256) void node_out_kernel(
    const float* __restrict__ sums, const int* __restrict__ cnt,
    const float* __restrict__ W1oT, const float* __restrict__ b1o,
    const float* __restrict__ W2o,  const float* __restrict__ b2o,
    float* __restrict__ fv)
{
    int idx = blockIdx.x * 256 + threadIdx.x;
    if (idx >= B * NN) return;
    int n = idx & (NN - 1);
    float inv = 1.f / fmaxf((float)cnt[n], 1.f);
    const float4* sp = (const float4*)(sums + ((size_t)idx << 5));

    float f1[32];
    #pragma unroll
    for (int o = 0; o < 32; ++o) f1[o] = b1o[o];
    #pragma unroll
    for (int q = 0; q < 8; ++q) {
        float4 v = sp[q];
        float xv[4] = {v.x, v.y, v.z, v.w};
        #pragma unroll
        for (int c = 0; c < 4; ++c) {
            float x = xv[c] * inv;
            int j = q * 4 + c;
            #pragma unroll
            for (int o = 0; o < 32; ++o) f1[o] += x * W1oT[j * 32 + o];
        }
    }
    float f2 = b2o[0];
    #pragma unroll
    for (int j = 0; j < 32; ++j) f2 += fmaxf(f1[j], 0.f) * W2o[j];
    fv[idx] = lrelu(f2);
}

// ---------------- final reduction ----------------
__global__ __launch_bounds__(256) void final_kernel(
    const float* __restrict__ fv, const float* __restrict__ Wg,
    const float* __restrict__ bg, float* __restrict__ out)
{
    int b = blockIdx.x;
    int t = threadIdx.x;
    float p = 0.f;
    for (int n = t; n < NN; n += 256) p += fv[(size_t)b * NN + n] * Wg[n];
    __shared__ float red[256];
    red[t] = p;
    __syncthreads();
    for (int s = 128; s > 0; s >>= 1) {
        if (t < s) red[t] += red[t + s];
        __syncthreads();
    }
    if (t == 0) {
        float x = red[0] + bg[0];
        out[b] = 1.f / (1.f + expf(-x));
    }
}

extern "C" void kernel_launch(void* const* d_in, const int* in_sizes, int n_in,
                              void* d_out, int out_size, void* d_ws, size_t ws_size,
                              hipStream_t stream)
{
    const float* vert = (const float*)d_in[0];
    const int*   edges = (const int*)d_in[1];
    const float* Wx  = (const float*)d_in[2];
    const float* bx  = (const float*)d_in[3];
    const float* Wy  = (const float*)d_in[4];
    const float* by  = (const float*)d_in[5];
    const float* Wth = (const float*)d_in[6];
    const float* bth = (const float*)d_in[7];
    const float* W1c = (const float*)d_in[8];
    const float* b1c = (const float*)d_in[9];
    const float* W2c = (const float*)d_in[10];
    const float* b2c = (const float*)d_in[11];
    const float* W1v = (const float*)d_in[12];
    const float* b1v = (const float*)d_in[13];
    const float* W2v = (const float*)d_in[14];
    const float* b2v = (const float*)d_in[15];
    const float* W1e = (const float*)d_in[16];
    const float* b1e = (const float*)d_in[17];
    const float* W2e = (const float*)d_in[18];
    const float* b2e = (const float*)d_in[19];
    const float* W1o = (const float*)d_in[20];
    const float* b1o = (const float*)d_in[21];
    const float* W2o = (const float*)d_in[22];
    const float* b2o = (const float*)d_in[23];
    const float* Wg  = (const float*)d_in[24];
    const float* bg  = (const float*)d_in[25];
    float* out = (float*)d_out;

    // workspace layout (~17.9 MB)
    char* w = (char*)d_ws;
    unsigned int* asrc = (unsigned int*)w; w += (size_t)B * NN * 32 * 2;  // bf16
    unsigned int* adst = (unsigned int*)w; w += (size_t)B * NN * 32 * 2;  // bf16
    float* sums = (float*)w; w += (size_t)B * NN * 32 * 4;
    float* fv   = (float*)w; w += (size_t)B * NN * 4;
    float* W1cT = (float*)w; w += 32 * 24 * 4;
    float* W2cT = (float*)w; w += 32 * 32 * 4;
    float* W1vT = (float*)w; w += 32 * 64 * 4;
    float* W2vT = (float*)w; w += 32 * 32 * 4;
    float* W1sT = (float*)w; w += 34 * 32 * 4;
    float* W1dT = (float*)w; w += 34 * 32 * 4;
    float* W2eT = (float*)w; w += 32 * 32 * 4;
    float* W1oT = (float*)w; w += 32 * 32 * 4;
    int* cnt    = (int*)w;   w += NN * 4;
    int* cursor = (int*)w;   w += NN * 4;
    int* offs   = (int*)w;   w += NN * 4;
    int* elist  = (int*)w;   w += E * 4;
    int* dlist  = (int*)w;   w += E * 4;

    prep_kernel<<<1, 1024, 0, stream>>>(W1c, W2c, W1v, W2v, W1e, W2e, W1o,
                                        W1cT, W2cT, W1vT, W2vT, W1sT, W1dT, W2eT, W1oT);
    zero_kernel<<<2048, 256, 0, stream>>>(sums, cnt, cursor);
    count_kernel<<<E / 256, 256, 0, stream>>>(edges, cnt);
    scan_kernel<<<1, 1024, 0, stream>>>(cnt, offs);
    fill_kernel<<<E / 256, 256, 0, stream>>>(edges, offs, cursor, elist, dlist);

    vertex_kernel<<<(B * NN) / 256, 256, 0, stream>>>(
        vert, Wx, bx, Wy, by, Wth, bth, b1c, b2c, b1v, b2v, b1e,
        W1cT, W2cT, W1vT, W2vT, W1sT, W1dT, asrc, adst);

    edge_kernel<<<(B * E) / 256, 256, 0, stream>>>(
        asrc, adst, elist, dlist, W2eT, b2e, sums);

    node_out_kernel<<<(B * NN) / 256, 256, 0, stream>>>(
        sums, cnt, W1oT, b1o, W2o, b2o, fv);

    final_kernel<<<B, 256, 0, stream>>>(fv, Wg, bg, out);
}

// Round 4
// 252.359 us; speedup vs baseline: 4.8802x; 1.4758x over previous
//
#include <hip/hip_runtime.h>
#include <math.h>

constexpr int B = 32;
constexpr int NN = 2048;   // nodes
constexpr int E = 65536;   // edges
constexpr float SLOPE = 0.01f;

typedef __attribute__((ext_vector_type(8))) short bf16x8;
typedef __attribute__((ext_vector_type(4))) float f32x4;

__device__ __forceinline__ float lrelu(float x) { return x > 0.f ? x : SLOPE * x; }

__device__ __forceinline__ unsigned int pack_bf16(float lo, float hi) {
    unsigned int a = __float_as_uint(lo);
    unsigned int b = __float_as_uint(hi);
    a += 0x7fffu + ((a >> 16) & 1u);
    b += 0x7fffu + ((b >> 16) & 1u);
    return (a >> 16) | (b & 0xffff0000u);
}

__device__ __forceinline__ void unpack_bf16(unsigned int u, float& lo, float& hi) {
    lo = __uint_as_float(u << 16);
    hi = __uint_as_float(u & 0xffff0000u);
}

// ---------------- prep: transposed weights + bf16 W2e ----------------
__global__ __launch_bounds__(1024) void prep_kernel(
    const float* __restrict__ W1c, const float* __restrict__ W2c,
    const float* __restrict__ W1v, const float* __restrict__ W2v,
    const float* __restrict__ W1e, const float* __restrict__ W2e,
    const float* __restrict__ W1o,
    float* __restrict__ W1cT, float* __restrict__ W2cT,
    float* __restrict__ W1vT, float* __restrict__ W2vT,
    float* __restrict__ W1sT, float* __restrict__ W1dT,
    unsigned short* __restrict__ W2eb, float* __restrict__ W1oT)
{
    int t = threadIdx.x;
    for (int i = t; i < 32 * 24; i += 1024) W1cT[(i % 24) * 32 + i / 24] = W1c[i];
    for (int i = t; i < 32 * 32; i += 1024) W2cT[(i % 32) * 32 + i / 32] = W2c[i];
    for (int i = t; i < 32 * 64; i += 1024) W1vT[(i % 64) * 32 + i / 64] = W1v[i];
    for (int i = t; i < 32 * 32; i += 1024) W2vT[(i % 32) * 32 + i / 32] = W2v[i];
    for (int i = t; i < 32 * 68; i += 1024) {
        int o = i / 68, j = i % 68;
        if (j < 34) W1sT[j * 32 + o] = W1e[i];
        else        W1dT[(j - 34) * 32 + o] = W1e[i];
    }
    for (int i = t; i < 32 * 32; i += 1024) {       // W2e row-major f32 -> bf16 (RNE)
        unsigned int u = __float_as_uint(W2e[i]);
        u += 0x7fffu + ((u >> 16) & 1u);
        W2eb[i] = (unsigned short)(u >> 16);
    }
    for (int i = t; i < 32 * 32; i += 1024) W1oT[(i % 32) * 32 + i / 32] = W1o[i];
}

// ---------------- CSR build ----------------
__global__ __launch_bounds__(256) void zero_kernel(int* __restrict__ cnt, int* __restrict__ cursor)
{
    int i = blockIdx.x * 256 + threadIdx.x;
    if (i < NN) { cnt[i] = 0; cursor[i] = 0; }
}

__global__ __launch_bounds__(256) void count_kernel(const int* __restrict__ edges, int* __restrict__ cnt)
{
    int e = blockIdx.x * 256 + threadIdx.x;
    if (e < E) atomicAdd(&cnt[edges[E + e]], 1);
}

__global__ __launch_bounds__(1024) void scan_kernel(const int* __restrict__ cnt, int* __restrict__ offs)
{
    __shared__ int s[1024];
    int t = threadIdx.x;
    int c0 = cnt[2 * t], c1 = cnt[2 * t + 1];
    int own = c0 + c1;
    s[t] = own;
    __syncthreads();
    int v = own;
    for (int d = 1; d < 1024; d <<= 1) {
        int add = (t >= d) ? s[t - d] : 0;
        __syncthreads();
        v += add;
        s[t] = v;
        __syncthreads();
    }
    int excl = v - own;
    offs[2 * t] = excl;
    offs[2 * t + 1] = excl + c0;
    if (t == 1023) offs[2048] = v;       // total = E
}

__global__ __launch_bounds__(256) void fill_kernel(
    const int* __restrict__ edges, const int* __restrict__ offs,
    int* __restrict__ cursor, int* __restrict__ elist)
{
    int e = blockIdx.x * 256 + threadIdx.x;
    if (e < E) {
        int d = edges[E + e];
        int p = atomicAdd(&cursor[d], 1);
        elist[offs[d] + p] = edges[e];
    }
}

// ---------------- vertex MLP + per-node edge-layer-1 projections (bf16) ----------------
__global__ __launch_bounds__(256) void vertex_kernel(
    const float* __restrict__ vert,
    const float* __restrict__ Wx,  const float* __restrict__ bx,
    const float* __restrict__ Wy,  const float* __restrict__ by,
    const float* __restrict__ Wth, const float* __restrict__ bth,
    const float* __restrict__ b1c, const float* __restrict__ b2c,
    const float* __restrict__ b1v, const float* __restrict__ b2v,
    const float* __restrict__ b1e,
    const float* __restrict__ W1cT, const float* __restrict__ W2cT,
    const float* __restrict__ W1vT, const float* __restrict__ W2vT,
    const float* __restrict__ W1sT, const float* __restrict__ W1dT,
    unsigned int* __restrict__ asrc, unsigned int* __restrict__ adst)
{
    int idx = blockIdx.x * 256 + threadIdx.x;
    if (idx >= B * NN) return;
    const float* v = vert + (size_t)idx * 11;
    float qk0 = v[0], qk1 = v[1], qk2 = v[2];
    float q00 = v[3], q01 = v[4], q02 = v[5];
    float qg0 = v[6], qg1 = v[7], qg2 = v[8];
    float col0 = v[9], col1 = v[10];

    float cf[64];
    #pragma unroll
    for (int half = 0; half < 2; ++half) {
        float a0 = half ? qg0 : q00;
        float a1 = half ? qg1 : q01;
        float a2 = half ? qg2 : q02;
        float c[24];
        #pragma unroll
        for (int k = 0; k < 8; ++k) {
            c[k]      = lrelu(qk0 * Wx[2 * k]  + a0 * Wx[2 * k + 1]  + bx[k]);
            c[8 + k]  = lrelu(qk1 * Wy[2 * k]  + a1 * Wy[2 * k + 1]  + by[k]);
            c[16 + k] = lrelu(qk2 * Wth[2 * k] + a2 * Wth[2 * k + 1] + bth[k]);
        }
        float h[32];
        #pragma unroll
        for (int o = 0; o < 32; ++o) h[o] = b1c[o];
        #pragma unroll
        for (int j = 0; j < 24; ++j) {
            float x = c[j];
            #pragma unroll
            for (int o = 0; o < 32; ++o) h[o] += x * W1cT[j * 32 + o];
        }
        #pragma unroll
        for (int o = 0; o < 32; ++o) h[o] = lrelu(h[o]);
        float g[32];
        #pragma unroll
        for (int o = 0; o < 32; ++o) g[o] = b2c[o];
        #pragma unroll
        for (int j = 0; j < 32; ++j) {
            float x = h[j];
            #pragma unroll
            for (int o = 0; o < 32; ++o) g[o] += x * W2cT[j * 32 + o];
        }
        #pragma unroll
        for (int o = 0; o < 32; ++o) cf[half * 32 + o] = lrelu(g[o]);
    }

    float v1[32];
    #pragma unroll
    for (int o = 0; o < 32; ++o) v1[o] = b1v[o];
    #pragma unroll
    for (int j = 0; j < 64; ++j) {
        float x = cf[j];
        #pragma unroll
        for (int o = 0; o < 32; ++o) v1[o] += x * W1vT[j * 32 + o];
    }
    #pragma unroll
    for (int o = 0; o < 32; ++o) v1[o] = lrelu(v1[o]);

    float v2[32];
    #pragma unroll
    for (int o = 0; o < 32; ++o) v2[o] = b2v[o];
    #pragma unroll
    for (int j = 0; j < 32; ++j) {
        float x = v1[j];
        #pragma unroll
        for (int o = 0; o < 32; ++o) v2[o] += x * W2vT[j * 32 + o];
    }

    float vfr[34];
    #pragma unroll
    for (int o = 0; o < 32; ++o) vfr[o] = lrelu(v2[o]);
    vfr[32] = col0;
    vfr[33] = col1;

    float as[32], ad[32];
    #pragma unroll
    for (int o = 0; o < 32; ++o) { as[o] = 0.f; ad[o] = b1e[o]; }
    #pragma unroll
    for (int j = 0; j < 34; ++j) {
        float x = vfr[j];
        #pragma unroll
        for (int o = 0; o < 32; ++o) {
            as[o] += x * W1sT[j * 32 + o];
            ad[o] += x * W1dT[j * 32 + o];
        }
    }

    unsigned int* ps = asrc + ((size_t)idx << 4);   // 16 uints = 32 bf16
    unsigned int* pd = adst + ((size_t)idx << 4);
    #pragma unroll
    for (int q = 0; q < 16; ++q) {
        ps[q] = pack_bf16(as[2 * q], as[2 * q + 1]);
        pd[q] = pack_bf16(ad[2 * q], ad[2 * q + 1]);
    }
}

// ---------------- edge phase: MFMA over 16-edge chunks, per-dst waves,
//                  fused mean + node output MLP ----------------
__global__ __launch_bounds__(256, 6) void edge_kernel(
    const unsigned int* __restrict__ asrc, const unsigned int* __restrict__ adst,
    const int* __restrict__ elist, const int* __restrict__ offs,
    const unsigned short* __restrict__ W2eb, const float* __restrict__ b2e,
    const float* __restrict__ W1oT, const float* __restrict__ b1o,
    const float* __restrict__ W2o,  const float* __restrict__ b2o,
    float* __restrict__ fv)
{
    constexpr int DPW = 8;                          // dsts per wave
    int lane = threadIdx.x & 63;
    int gw = blockIdx.x * 4 + (threadIdx.x >> 6);   // 8192 waves total
    int b = gw >> 8;                                // NN/DPW = 256 waves per batch
    int d0 = (gw & 255) * DPW;
    int col = lane & 15;
    int grp = lane >> 4;

    // B fragments: lane needs B[k][n] = W2e[n][k], k = grp*8+j, contiguous bf16
    union U8 { unsigned int u[4]; bf16x8 v; uint4 q; };
    U8 Bf0, Bf1;
    Bf0.q = *(const uint4*)(W2eb + col * 32 + grp * 8);
    Bf1.q = *(const uint4*)(W2eb + (col + 16) * 32 + grp * 8);
    float bias0 = b2e[col];
    float bias1 = b2e[col + 16];
    float w2oc = W2o[lane & 31];
    float b1oc = b1o[lane & 31];

    for (int dd = 0; dd < DPW; ++dd) {
        int d = d0 + dd;
        int start = offs[d];
        int end = offs[d + 1];
        int deg = end - start;

        // adst for this dst: lane's k-slice (8 values), unpacked to f32
        const uint4 du = *(const uint4*)(adst + (((size_t)(b * NN + d)) << 4) + grp * 4);
        float adr[8];
        unpack_bf16(du.x, adr[0], adr[1]);
        unpack_bf16(du.y, adr[2], adr[3]);
        unpack_bf16(du.z, adr[4], adr[5]);
        unpack_bf16(du.w, adr[6], adr[7]);

        float s0 = 0.f, s1 = 0.f;
        for (int e0 = start; e0 < end; e0 += 16) {
            int e = e0 + col;
            int ec = e < end ? e : end - 1;
            int src = elist[ec];
            const uint4 su = *(const uint4*)(asrc + (((size_t)(b * NN + src)) << 4) + grp * 4);
            float h[8];
            {
                float lo, hi;
                unpack_bf16(su.x, lo, hi);
                h[0] = fmaxf(lo + adr[0], 0.f); h[1] = fmaxf(hi + adr[1], 0.f);
                unpack_bf16(su.y, lo, hi);
                h[2] = fmaxf(lo + adr[2], 0.f); h[3] = fmaxf(hi + adr[3], 0.f);
                unpack_bf16(su.z, lo, hi);
                h[4] = fmaxf(lo + adr[4], 0.f); h[5] = fmaxf(hi + adr[5], 0.f);
                unpack_bf16(su.w, lo, hi);
                h[6] = fmaxf(lo + adr[6], 0.f); h[7] = fmaxf(hi + adr[7], 0.f);
            }
            U8 A;
            A.u[0] = pack_bf16(h[0], h[1]);
            A.u[1] = pack_bf16(h[2], h[3]);
            A.u[2] = pack_bf16(h[4], h[5]);
            A.u[3] = pack_bf16(h[6], h[7]);

            f32x4 acc0 = {bias0, bias0, bias0, bias0};
            f32x4 acc1 = {bias1, bias1, bias1, bias1};
            acc0 = __builtin_amdgcn_mfma_f32_16x16x32_bf16(A.v, Bf0.v, acc0, 0, 0, 0);
            acc1 = __builtin_amdgcn_mfma_f32_16x16x32_bf16(A.v, Bf1.v, acc1, 0, 0, 0);

            int rowbase = e0 + grp * 4;             // D row = grp*4+r -> edge e0+grp*4+r
            #pragma unroll
            for (int r = 0; r < 4; ++r) {
                bool valid = (rowbase + r) < end;
                s0 += valid ? lrelu(acc0[r]) : 0.f;
                s1 += valid ? lrelu(acc1[r]) : 0.f;
            }
        }

        // reduce across the 4 lane-groups: all lanes end with col sums
        s0 += __shfl_xor(s0, 16); s0 += __shfl_xor(s0, 32);
        s1 += __shfl_xor(s1, 16); s1 += __shfl_xor(s1, 32);

        // fused node MLP: agg -> W1o/relu -> W2o dot -> lrelu
        float inv = 1.f / fmaxf((float)deg, 1.f);
        float a0 = s0 * inv;                        // agg[col]      (lane col = lane&15)
        float a1 = s1 * inv;                        // agg[col+16]
        int o = lane & 31;
        float f1 = b1oc;
        #pragma unroll
        for (int j = 0; j < 16; ++j) {
            float aj = __shfl(a0, j);               // agg[j]
            f1 += aj * W1oT[j * 32 + o];
            float ak = __shfl(a1, j);               // agg[16+j]
            f1 += ak * W1oT[(16 + j) * 32 + o];
        }
        float t = fmaxf(f1, 0.f) * w2oc;
        t += __shfl_xor(t, 1);
        t += __shfl_xor(t, 2);
        t += __shfl_xor(t, 4);
        t += __shfl_xor(t, 8);
        t += __shfl_xor(t, 16);
        if (lane == 0) fv[(size_t)b * NN + d] = lrelu(t + b2o[0]);
    }
}

// ---------------- final: out[b] = sigmoid(dot(fv[b,:], Wg) + bg) ----------------
__global__ __launch_bounds__(256) void final_kernel(
    const float* __restrict__ fv, const float* __restrict__ Wg,
    const float* __restrict__ bg, float* __restrict__ out)
{
    int b = blockIdx.x;
    int t = threadIdx.x;
    float p = 0.f;
    for (int n = t; n < NN; n += 256) p += fv[(size_t)b * NN + n] * Wg[n];
    __shared__ float red[256];
    red[t] = p;
    __syncthreads();
    for (int s = 128; s > 0; s >>= 1) {
        if (t < s) red[t] += red[t + s];
        __syncthreads();
    }
    if (t == 0) {
        float x = red[0] + bg[0];
        out[b] = 1.f / (1.f + expf(-x));
    }
}

extern "C" void kernel_launch(void* const* d_in, const int* in_sizes, int n_in,
                              void* d_out, int out_size, void* d_ws, size_t ws_size,
                              hipStream_t stream)
{
    const float* vert = (const float*)d_in[0];
    const int*   edges = (const int*)d_in[1];
    const float* Wx  = (const float*)d_in[2];
    const float* bx  = (const float*)d_in[3];
    const float* Wy  = (const float*)d_in[4];
    const float* by  = (const float*)d_in[5];
    const float* Wth = (const float*)d_in[6];
    const float* bth = (const float*)d_in[7];
    const float* W1c = (const float*)d_in[8];
    const float* b1c = (const float*)d_in[9];
    const float* W2c = (const float*)d_in[10];
    const float* b2c = (const float*)d_in[11];
    const float* W1v = (const float*)d_in[12];
    const float* b1v = (const float*)d_in[13];
    const float* W2v = (const float*)d_in[14];
    const float* b2v = (const float*)d_in[15];
    const float* W1e = (const float*)d_in[16];
    const float* b1e = (const float*)d_in[17];
    const float* W2e = (const float*)d_in[18];
    const float* b2e = (const float*)d_in[19];
    const float* W1o = (const float*)d_in[20];
    const float* b1o = (const float*)d_in[21];
    const float* W2o = (const float*)d_in[22];
    const float* b2o = (const float*)d_in[23];
    const float* Wg  = (const float*)d_in[24];
    const float* bg  = (const float*)d_in[25];
    float* out = (float*)d_out;

    // workspace layout (~9 MB, all chunks 16B-aligned)
    char* w = (char*)d_ws;
    unsigned int* asrc = (unsigned int*)w; w += (size_t)B * NN * 32 * 2;  // bf16 pairs
    unsigned int* adst = (unsigned int*)w; w += (size_t)B * NN * 32 * 2;
    float* fv   = (float*)w; w += (size_t)B * NN * 4;
    float* W1cT = (float*)w; w += 32 * 24 * 4;
    float* W2cT = (float*)w; w += 32 * 32 * 4;
    float* W1vT = (float*)w; w += 32 * 64 * 4;
    float* W2vT = (float*)w; w += 32 * 32 * 4;
    float* W1sT = (float*)w; w += 34 * 32 * 4;
    float* W1dT = (float*)w; w += 34 * 32 * 4;
    float* W1oT = (float*)w; w += 32 * 32 * 4;
    unsigned short* W2eb = (unsigned short*)w; w += 32 * 32 * 2;
    int* cnt    = (int*)w;   w += NN * 4;
    int* cursor = (int*)w;   w += NN * 4;
    int* offs   = (int*)w;   w += 2052 * 4;          // NN+1 used, padded to 16B
    int* elist  = (int*)w;   w += E * 4;

    prep_kernel<<<1, 1024, 0, stream>>>(W1c, W2c, W1v, W2v, W1e, W2e, W1o,
                                        W1cT, W2cT, W1vT, W2vT, W1sT, W1dT, W2eb, W1oT);
    zero_kernel<<<(NN + 255) / 256, 256, 0, stream>>>(cnt, cursor);
    count_kernel<<<E / 256, 256, 0, stream>>>(edges, cnt);
    scan_kernel<<<1, 1024, 0, stream>>>(cnt, offs);
    fill_kernel<<<E / 256, 256, 0, stream>>>(edges, offs, cursor, elist);

    vertex_kernel<<<(B * NN) / 256, 256, 0, stream>>>(
        vert, Wx, bx, Wy, by, Wth, bth, b1c, b2c, b1v, b2v, b1e,
        W1cT, W2cT, W1vT, W2vT, W1sT, W1dT, asrc, adst);

    edge_kernel<<<(B * NN / 8) / 4, 256, 0, stream>>>(
        asrc, adst, elist, offs, W2eb, b2e, W1oT, b1o, W2o, b2o, fv);

    final_kernel<<<B, 256, 0, stream>>>(fv, Wg, bg, out);
}